// Round 14
// baseline (70.067 us; speedup 1.0000x reference)
//
#include <hip/hip_runtime.h>
#include <hip/hip_bf16.h>
#include <math.h>

// Problem constants (fixed by reference)
constexpr int Bsz = 4;
constexpr int SEQ = 2048;
constexpr int DM  = 512;
constexpr int NH  = 8;
constexpr int HD  = 64;      // DM / NH
constexpr int LAG = 10;      // MAX_LAG
constexpr int MROWS = Bsz * SEQ;                        // 8192
constexpr size_t OUT0_ELEMS = (size_t)Bsz * SEQ * DM;   // 4,194,304
constexpr int NQKV = 3 * DM;                            // 1536

typedef __attribute__((ext_vector_type(8))) short short8;
typedef __attribute__((ext_vector_type(4))) float f32x4;
typedef __attribute__((ext_vector_type(16))) float f32x16;

__device__ __forceinline__ float bf2f(unsigned short u) {
  union { unsigned int i; float f; } x; x.i = (unsigned int)u << 16; return x.f;
}
__device__ __forceinline__ unsigned short f2bf(float f) {
  __hip_bfloat16 h = __float2bfloat16(f);
  return *(unsigned short*)&h;
}

// ---------------------------------------------------------------------------
// async global -> LDS, 16B per lane. LDS dest is wave-uniform base + lane*16.
// ---------------------------------------------------------------------------
__device__ __forceinline__ void gload_lds16(const void* g, void* l) {
  __builtin_amdgcn_global_load_lds(
      (const __attribute__((address_space(1))) unsigned int*)g,
      (__attribute__((address_space(3))) unsigned int*)l, 16, 0, 0);
}

// ---------------------------------------------------------------------------
// Fused prep: blocks [0,2048) cast x f32->bf16; [2048,3072) transpose+cast
// weights; block 3072 concatenates biases.
// ---------------------------------------------------------------------------
__global__ __launch_bounds__(256) void prep(
    const float* __restrict__ x, const float* __restrict__ Wq,
    const float* __restrict__ Wk, const float* __restrict__ Wv,
    const float* __restrict__ Wo, const float* __restrict__ bq,
    const float* __restrict__ bk, const float* __restrict__ bv,
    __hip_bfloat16* __restrict__ xb, __hip_bfloat16* __restrict__ Wtqkv,
    __hip_bfloat16* __restrict__ Wot, float* __restrict__ bcat) {
  __shared__ float t[32][33];
  const int blk = blockIdx.x;
  const int tid = threadIdx.x;
  if (blk < 2048) {
    // x cast, 8 elems/thread
    size_t i = ((size_t)blk * 256 + tid) * 8;
    float4 a = *(const float4*)(x + i);
    float4 b = *(const float4*)(x + i + 4);
    union { unsigned short h[8]; uint4 u; } pk;
    pk.h[0] = f2bf(a.x); pk.h[1] = f2bf(a.y); pk.h[2] = f2bf(a.z); pk.h[3] = f2bf(a.w);
    pk.h[4] = f2bf(b.x); pk.h[5] = f2bf(b.y); pk.h[6] = f2bf(b.z); pk.h[7] = f2bf(b.w);
    *(uint4*)(xb + i) = pk.u;
  } else if (blk < 3072) {
    const int zb = blk - 2048;
    const int z = zb >> 8, rem = zb & 255;
    const float* W = (z == 0) ? Wq : (z == 1) ? Wk : (z == 2) ? Wv : Wo;
    __hip_bfloat16* dst = (z < 3) ? (Wtqkv + (size_t)z * DM * DM) : Wot;
    const int n0 = (rem & 15) * 32, k0 = (rem >> 4) * 32;
    const int tx = tid & 31, ty = tid >> 5;
#pragma unroll
    for (int r = 0; r < 4; r++)
      t[ty + r * 8][tx] = W[(size_t)(k0 + ty + r * 8) * DM + n0 + tx];
    __syncthreads();
#pragma unroll
    for (int r = 0; r < 4; r++)
      dst[(size_t)(n0 + ty + r * 8) * DM + k0 + tx] =
          __float2bfloat16(t[tx][ty + r * 8]);
  } else {
    for (int i = tid; i < NQKV; i += 256)
      bcat[i] = (i < 512) ? bq[i] : (i < 1024) ? bk[i - 512] : bv[i - 1024];
  }
}

// ---------------------------------------------------------------------------
// QKV GEMM: qkv[8192,1536] = xb[8192,512] @ Wtqkv^T + bcat, bf16 out.
// 256x192 tile, BK=64, 8 waves (4M x 2N), 32x32x16 MFMA, stage-ahead dbuf.
// Fill REMOVED (moved to band_attn): barriers now wait only on stage loads,
// not on 28 KB of nontemporal HBM store-acks per K-step (r13 theory).
// ---------------------------------------------------------------------------
__global__ __launch_bounds__(512) void qkv_gemm(
    const __hip_bfloat16* __restrict__ A, const __hip_bfloat16* __restrict__ Bt,
    const float* __restrict__ bias, __hip_bfloat16* __restrict__ C) {
  __shared__ __align__(16) char smem[114688];   // 2 x (32K A + 24K B)

  // XCD-aware bijective swizzle (grid 256, 32 M-tiles x 8 N-tiles)
  int lin = blockIdx.x;
  lin = (lin & 7) * 32 + (lin >> 3);
  const int bm = (lin >> 3) * 256;
  const int bn = (lin & 7) * 192;

  const int tid = threadIdx.x;
  const int lane = tid & 63, wave = tid >> 6;
  const int wr = wave >> 1, wc = wave & 1;      // 4M x 2N wave grid
  const int l31 = lane & 31, lhi = lane >> 5;

  f32x16 acc[2][3] = {};

  // ---- staging helper (A: 4 chunks, B: 3 chunks per thread) ----
  auto STAGE = [&](int buf, int k0) {
    char* base = smem + buf * 57344;
#pragma unroll
    for (int it = 0; it < 4; ++it) {
      const int g = it * 512 + tid;
      const int row = g >> 3, ch = g & 7;
      const int src_ch = ch ^ (row & 7);        // inverse swizzle on SOURCE
      gload_lds16(A + (size_t)(bm + row) * DM + k0 + src_ch * 8,
                  base + (it * 512 + wave * 64) * 16);
    }
    char* baseB = base + 32768;
#pragma unroll
    for (int it = 0; it < 3; ++it) {
      const int g = it * 512 + tid;
      const int row = g >> 3, ch = g & 7;
      const int src_ch = ch ^ (row & 7);
      gload_lds16(Bt + (size_t)(bn + row) * DM + k0 + src_ch * 8,
                  baseB + (it * 512 + wave * 64) * 16);
    }
  };

  STAGE(0, 0);  // prologue

  for (int t = 0; t < 8; ++t) {
    __syncthreads();              // drains stage(t)
    if (t < 7) STAGE((t + 1) & 1, (t + 1) * 64);

    const char* As = smem + (t & 1) * 57344;
    const char* Bs = As + 32768;
#pragma unroll
    for (int kk = 0; kk < 4; ++kk) {   // 4 x K=16 sub-steps
      short8 a[2], b[3];
#pragma unroll
      for (int fi = 0; fi < 2; ++fi) {
        const int row = wr * 64 + fi * 32 + l31;
        const int ch = (kk * 2 + lhi) ^ (row & 7);
        a[fi] = *(const short8*)(As + row * 128 + ch * 16);
      }
#pragma unroll
      for (int fj = 0; fj < 3; ++fj) {
        const int row = wc * 96 + fj * 32 + l31;
        const int ch = (kk * 2 + lhi) ^ (row & 7);
        b[fj] = *(const short8*)(Bs + row * 128 + ch * 16);
      }
#pragma unroll
      for (int fi = 0; fi < 2; ++fi)
#pragma unroll
        for (int fj = 0; fj < 3; ++fj)
          acc[fi][fj] = __builtin_amdgcn_mfma_f32_32x32x16_bf16(
              a[fi], b[fj], acc[fi][fj], 0, 0, 0);
    }
  }

  // ---- epilogue: stage C in LDS (96 KB bf16), store coalesced ----
  __syncthreads();
  unsigned short (*Cs)[192] = (unsigned short (*)[192])smem;
#pragma unroll
  for (int fj = 0; fj < 3; ++fj) {
    const int col = wc * 96 + fj * 32 + l31;
    const float bv = bias[bn + col];
#pragma unroll
    for (int fi = 0; fi < 2; ++fi)
#pragma unroll
      for (int r = 0; r < 16; ++r) {
        const int row = wr * 64 + fi * 32 + (r & 3) + 8 * (r >> 2) + 4 * lhi;
        Cs[row][col] = f2bf(acc[fi][fj][r] + bv);
      }
  }
  __syncthreads();
#pragma unroll
  for (int it = 0; it < 12; ++it) {
    const int g = it * 512 + tid;       // 6144 chunks of 8 bf16, 24 per row
    const int row = g / 24, ch = g % 24;
    *(uint4*)(C + (size_t)(bm + row) * NQKV + bn + ch * 8) =
        *(const uint4*)&Cs[row][ch * 8];
  }
}

// ---------------------------------------------------------------------------
// bf16 MFMA GEMM (r4 structure) -- used for the O projection.
// ---------------------------------------------------------------------------
template <bool OUT_BF16>
__global__ __launch_bounds__(256) void gemm_mfma(
    const __hip_bfloat16* __restrict__ A, const __hip_bfloat16* __restrict__ Bt,
    const float* __restrict__ bias, void* __restrict__ Cout,
    int N, int K, int gx) {
  __shared__ __align__(16) char smem[32768];
  unsigned short (*As)[64] = (unsigned short (*)[64])smem;            // [128][64]
  unsigned short (*Bs)[64] = (unsigned short (*)[64])(smem + 16384);  // [128][64]

  // XCD-aware bijective swizzle
  int lin = blockIdx.x;
  const int cpx = gridDim.x >> 3;
  lin = (lin & 7) * cpx + (lin >> 3);
  const int bm = (lin / gx) * 128;
  const int bn = (lin % gx) * 128;

  const int tid = threadIdx.x;
  const int lane = tid & 63, wave = tid >> 6;
  const int wr = wave >> 1, wc = wave & 1;
  const int l31 = lane & 31, lhi = lane >> 5;

  f32x16 acc[2][2] = {};

  for (int k0 = 0; k0 < K; k0 += 64) {
#pragma unroll
    for (int it = 0; it < 4; ++it) {
      const int g = it * 256 + tid;
      const int row = g >> 3, ch = g & 7;
      const int src_ch = ch ^ (row & 7);  // inverse swizzle on SOURCE
      gload_lds16(A + (size_t)(bm + row) * K + k0 + src_ch * 8,
                  (char*)As + (it * 256 + wave * 64) * 16);
    }
#pragma unroll
    for (int it = 0; it < 4; ++it) {
      const int g = it * 256 + tid;
      const int row = g >> 3, ch = g & 7;
      const int src_ch = ch ^ (row & 7);
      gload_lds16(Bt + (size_t)(bn + row) * K + k0 + src_ch * 8,
                  (char*)Bs + (it * 256 + wave * 64) * 16);
    }
    __syncthreads();

#pragma unroll
    for (int kk = 0; kk < 4; ++kk) {
      short8 a[2], b[2];
#pragma unroll
      for (int fi = 0; fi < 2; ++fi) {
        const int row = wr * 64 + fi * 32 + l31;
        const int ch = (kk * 2 + lhi) ^ (row & 7);
        a[fi] = *(const short8*)((const char*)As + row * 128 + ch * 16);
      }
#pragma unroll
      for (int fj = 0; fj < 2; ++fj) {
        const int row = wc * 64 + fj * 32 + l31;
        const int ch = (kk * 2 + lhi) ^ (row & 7);
        b[fj] = *(const short8*)((const char*)Bs + row * 128 + ch * 16);
      }
#pragma unroll
      for (int fi = 0; fi < 2; ++fi)
#pragma unroll
        for (int fj = 0; fj < 2; ++fj)
          acc[fi][fj] = __builtin_amdgcn_mfma_f32_32x32x16_bf16(
              a[fi], b[fj], acc[fi][fj], 0, 0, 0);
    }
    __syncthreads();
  }

  // Epilogue staged through LDS.
  if (OUT_BF16) {
    unsigned short (*Cs)[128] = (unsigned short (*)[128])smem;
#pragma unroll
    for (int fj = 0; fj < 2; ++fj) {
      const float bv = bias[bn + wc * 64 + fj * 32 + l31];
      const int col = wc * 64 + fj * 32 + l31;
#pragma unroll
      for (int fi = 0; fi < 2; ++fi)
#pragma unroll
        for (int r = 0; r < 16; ++r) {
          const int row = wr * 64 + fi * 32 + (r & 3) + 8 * (r >> 2) + 4 * lhi;
          Cs[row][col] = f2bf(acc[fi][fj][r] + bv);
        }
    }
    __syncthreads();
    __hip_bfloat16* C = (__hip_bfloat16*)Cout;
#pragma unroll
    for (int t = 0; t < 8; ++t) {
      const int g = t * 256 + tid;
      const int row = g >> 4, ch = g & 15;
      *(uint4*)(C + (size_t)(bm + row) * N + bn + ch * 8) =
          *(const uint4*)&Cs[row][ch * 8];
    }
  } else {
    float (*Cs)[128] = (float (*)[128])smem;
    float* C = (float*)Cout;
#pragma unroll
    for (int half = 0; half < 2; ++half) {
      if (wr == half) {
#pragma unroll
        for (int fj = 0; fj < 2; ++fj) {
          const float bv = bias[bn + wc * 64 + fj * 32 + l31];
          const int col = wc * 64 + fj * 32 + l31;
#pragma unroll
          for (int fi = 0; fi < 2; ++fi)
#pragma unroll
            for (int r = 0; r < 16; ++r) {
              const int row = fi * 32 + (r & 3) + 8 * (r >> 2) + 4 * lhi;
              Cs[row][col] = acc[fi][fj][r] + bv;
            }
        }
      }
      __syncthreads();
#pragma unroll
      for (int t = 0; t < 8; ++t) {
        const int g = t * 256 + tid;
        const int row = g >> 5, ch = g & 31;
        *(float4*)(C + (size_t)(bm + half * 64 + row) * N + bn + ch * 4) =
            *(const float4*)&Cs[row][ch * 4];
      }
      __syncthreads();
    }
  }
}

// ---------------------------------------------------------------------------
// Banded causal attention -- one wave per row (r13 structure) + OWN-ROW FILL.
// Each wave now also zero-fills ITS OWN attn_out row (2048 f32 = 8 KB =
// 64 lanes x 8 f32x4): chunks outside the band window are zeroed vectorized;
// the <=16-slot aligned band window is written with scalar stores (band
// values + edge zeros). All stores are same-wave + disjoint-address -> no
// ordering hazard, and no barrier ever waits on them (unlike the old
// piggyback inside qkv_gemm's K-loop, whose __syncthreads vmcnt(0) drained
// 28 KB of store-acks every K-step at 1 block/CU).
// ---------------------------------------------------------------------------
__global__ __launch_bounds__(256) void band_attn(
    const __hip_bfloat16* __restrict__ qkv, const float* __restrict__ decay_p,
    __hip_bfloat16* __restrict__ ctx, float* __restrict__ attn_out) {
  __shared__ float dlds[LAG + 1];
  const int tid = threadIdx.x;
  if (tid <= LAG) {
    float p = decay_p[tid];
    float sp = fmaxf(p, 0.0f) + log1pf(expf(-fabsf(p)));  // stable softplus
    dlds[tid] = -logf(sp + 1e-8f);
  }
  __syncthreads();

  const int blk = blockIdx.x;                  // 0..2047
  const int wave = tid >> 6, lane = tid & 63;
  const int bi = ((blk & 7) << 10) + ((blk >> 3) << 2) + wave;  // XCD-affine
  const int b = bi >> 11;
  const int i = bi & (SEQ - 1);
  const int jlo = (i >= LAG) ? (i - LAG) : 0;
  const int nj = i - jlo + 1;

  // Band window, 4-aligned: [lo4, hi4) covers [jlo, i] exactly in chunks.
  const int lo4 = jlo & ~3;
  const int hi4 = (i | 3) + 1;

  float* arow = attn_out + (size_t)bi * SEQ;

  // ---- own-row zero-fill, vectorized, skipping the band chunks ----
  {
    const int c0 = lo4 >> 2, c1 = hi4 >> 2;
    f32x4 z = {0.f, 0.f, 0.f, 0.f};
#pragma unroll
    for (int t = 0; t < 8; ++t) {
      const int cid = t * 64 + lane;           // chunk of 4 f32
      if (cid < c0 || cid >= c1)
        __builtin_nontemporal_store(z, (f32x4*)arow + cid);
    }
  }

  // q: 16B/lane (dims 8*lane..8*lane+7)
  const uint4 qu = *(const uint4*)(
      (const unsigned short*)(qkv + (size_t)bi * NQKV) + lane * 8);
  const unsigned short* qp = (const unsigned short*)&qu;
  float qf[8];
#pragma unroll
  for (int e = 0; e < 8; ++e) qf[e] = bf2f(qp[e]);

  // scores: 11 dots, all heads at once
  float s[LAG + 1];
#pragma unroll
  for (int jj = 0; jj <= LAG; ++jj) {
    const int j = jlo + jj;
    const bool ok = (j <= i);
    const int jc = ok ? j : i;
    const uint4 ku = *(const uint4*)(
        (const unsigned short*)(qkv + ((size_t)b * SEQ + jc) * NQKV + DM) + lane * 8);
    const unsigned short* kp = (const unsigned short*)&ku;
    float part = 0.0f;
#pragma unroll
    for (int e = 0; e < 8; ++e) part += qf[e] * bf2f(kp[e]);
    part += __shfl_xor(part, 1);
    part += __shfl_xor(part, 2);
    part += __shfl_xor(part, 4);   // lanes 8h..8h+7 now hold q_h . k_h
    s[jj] = ok ? (part * 0.125f + dlds[i - j]) : -1e30f;
  }

  // softmax over band (in-register; identical within each 8-lane head group)
  float mx = -1e30f;
#pragma unroll
  for (int jj = 0; jj <= LAG; ++jj) mx = fmaxf(mx, s[jj]);
  float sum = 0.0f;
#pragma unroll
  for (int jj = 0; jj <= LAG; ++jj) { s[jj] = expf(s[jj] - mx); sum += s[jj]; }
  const float inv = 1.0f / sum;

  // PV accumulate (8 dims/lane); keep p in s[] for the head-mean
  float c[8] = {};
#pragma unroll
  for (int jj = 0; jj <= LAG; ++jj) {
    const float p = s[jj] * inv;
    s[jj] = p;
    const int j = jlo + jj;
    const int jc = (j <= i) ? j : i;
    const uint4 vu = *(const uint4*)(
        (const unsigned short*)(qkv + ((size_t)b * SEQ + jc) * NQKV + 2 * DM) + lane * 8);
    const unsigned short* vp = (const unsigned short*)&vu;
#pragma unroll
    for (int e = 0; e < 8; ++e) c[e] += p * bf2f(vp[e]);
  }

  // ctx store: pack 8 f32 -> 16B per lane (coalesced 1KB/row)
  unsigned short co[8];
#pragma unroll
  for (int e = 0; e < 8; ++e) co[e] = f2bf(c[e]);
  *(uint4*)((unsigned short*)(ctx + (size_t)bi * DM) + lane * 8) = *(const uint4*)co;

  // head-mean: reduce p across the 8 head groups (masks 8,16,32);
  // after this every lane holds mean_jj for each jj.
#pragma unroll
  for (int jj = 0; jj <= LAG; ++jj) {
    float a = s[jj];
    a += __shfl_xor(a, 8);
    a += __shfl_xor(a, 16);
    a += __shfl_xor(a, 32);
    s[jj] = a * 0.125f;
  }

  // band-window write: lane l covers position lo4+l (band value or edge 0).
  {
    float val = 0.0f;
    const int rel = lo4 + lane - jlo;          // target jj for this lane
#pragma unroll
    for (int jj = 0; jj <= LAG; ++jj)
      val = (rel == jj && jj < nj) ? s[jj] : val;
    if (lane < hi4 - lo4)
      __builtin_nontemporal_store(val, arow + lo4 + lane);
  }
}

// ---------------------------------------------------------------------------
extern "C" void kernel_launch(void* const* d_in, const int* in_sizes, int n_in,
                              void* d_out, int out_size, void* d_ws, size_t ws_size,
                              hipStream_t stream) {
  const float* x   = (const float*)d_in[0];
  const float* Wq  = (const float*)d_in[1];
  const float* bq  = (const float*)d_in[2];
  const float* Wk  = (const float*)d_in[3];
  const float* bk  = (const float*)d_in[4];
  const float* Wv  = (const float*)d_in[5];
  const float* bv  = (const float*)d_in[6];
  const float* Wo  = (const float*)d_in[7];
  const float* bo  = (const float*)d_in[8];
  const float* dec = (const float*)d_in[9];

  float* out      = (float*)d_out;                 // [B,S,D]
  float* attn_out = out + OUT0_ELEMS;              // [B,S,S]

  // Workspace layout (16B-aligned), ~44 MB
  char* w = (char*)d_ws;
  __hip_bfloat16* xb    = (__hip_bfloat16*)w;  w += (size_t)MROWS * DM * 2;
  __hip_bfloat16* Wtqkv = (__hip_bfloat16*)w;  w += (size_t)NQKV * DM * 2;
  __hip_bfloat16* Wot   = (__hip_bfloat16*)w;  w += (size_t)DM * DM * 2;
  float*          bcat  = (float*)w;           w += (size_t)NQKV * 4;
  __hip_bfloat16* qkv   = (__hip_bfloat16*)w;  w += (size_t)MROWS * NQKV * 2;
  __hip_bfloat16* ctxb  = (__hip_bfloat16*)w;

  prep<<<3073, 256, 0, stream>>>(x, Wq, Wk, Wv, Wo, bq, bk, bv,
                                 xb, Wtqkv, Wot, bcat);

  // Fused QKV projection (256x192 tile, dbuf stage-ahead; no fill)
  qkv_gemm<<<256, 512, 0, stream>>>(xb, Wtqkv, bcat, qkv);

  band_attn<<<2048, 256, 0, stream>>>(qkv, dec, ctxb, attn_out);

  // Output projection: [8192,512] @ [512,512] -> f32 out
  gemm_mfma<false><<<256, 256, 0, stream>>>(ctxb, Wot, bo, out,
                                            DM, DM, DM / 128);
}

// Round 15
// 64.234 us; speedup vs baseline: 1.0908x; 1.0908x over previous
//
#include <hip/hip_runtime.h>
#include <hip/hip_bf16.h>
#include <math.h>

// Problem constants (fixed by reference)
constexpr int Bsz = 4;
constexpr int SEQ = 2048;
constexpr int DM  = 512;
constexpr int NH  = 8;
constexpr int HD  = 64;      // DM / NH
constexpr int LAG = 10;      // MAX_LAG
constexpr int MROWS = Bsz * SEQ;                        // 8192
constexpr size_t OUT0_ELEMS = (size_t)Bsz * SEQ * DM;   // 4,194,304
constexpr int NQKV = 3 * DM;                            // 1536

typedef __attribute__((ext_vector_type(8))) short short8;
typedef __attribute__((ext_vector_type(4))) float f32x4;
typedef __attribute__((ext_vector_type(16))) float f32x16;

__device__ __forceinline__ float bf2f(unsigned short u) {
  union { unsigned int i; float f; } x; x.i = (unsigned int)u << 16; return x.f;
}
__device__ __forceinline__ unsigned short f2bf(float f) {
  __hip_bfloat16 h = __float2bfloat16(f);
  return *(unsigned short*)&h;
}

// ---------------------------------------------------------------------------
// async global -> LDS, 16B per lane. LDS dest is wave-uniform base + lane*16.
// ---------------------------------------------------------------------------
__device__ __forceinline__ void gload_lds16(const void* g, void* l) {
  __builtin_amdgcn_global_load_lds(
      (const __attribute__((address_space(1))) unsigned int*)g,
      (__attribute__((address_space(3))) unsigned int*)l, 16, 0, 0);
}

// ---------------------------------------------------------------------------
// Fused prep: blocks [0,2048) cast x f32->bf16; [2048,3072) transpose+cast
// weights; block 3072 concatenates biases.
// ---------------------------------------------------------------------------
__global__ __launch_bounds__(256) void prep(
    const float* __restrict__ x, const float* __restrict__ Wq,
    const float* __restrict__ Wk, const float* __restrict__ Wv,
    const float* __restrict__ Wo, const float* __restrict__ bq,
    const float* __restrict__ bk, const float* __restrict__ bv,
    __hip_bfloat16* __restrict__ xb, __hip_bfloat16* __restrict__ Wtqkv,
    __hip_bfloat16* __restrict__ Wot, float* __restrict__ bcat) {
  __shared__ float t[32][33];
  const int blk = blockIdx.x;
  const int tid = threadIdx.x;
  if (blk < 2048) {
    // x cast, 8 elems/thread
    size_t i = ((size_t)blk * 256 + tid) * 8;
    float4 a = *(const float4*)(x + i);
    float4 b = *(const float4*)(x + i + 4);
    union { unsigned short h[8]; uint4 u; } pk;
    pk.h[0] = f2bf(a.x); pk.h[1] = f2bf(a.y); pk.h[2] = f2bf(a.z); pk.h[3] = f2bf(a.w);
    pk.h[4] = f2bf(b.x); pk.h[5] = f2bf(b.y); pk.h[6] = f2bf(b.z); pk.h[7] = f2bf(b.w);
    *(uint4*)(xb + i) = pk.u;
  } else if (blk < 3072) {
    const int zb = blk - 2048;
    const int z = zb >> 8, rem = zb & 255;
    const float* W = (z == 0) ? Wq : (z == 1) ? Wk : (z == 2) ? Wv : Wo;
    __hip_bfloat16* dst = (z < 3) ? (Wtqkv + (size_t)z * DM * DM) : Wot;
    const int n0 = (rem & 15) * 32, k0 = (rem >> 4) * 32;
    const int tx = tid & 31, ty = tid >> 5;
#pragma unroll
    for (int r = 0; r < 4; r++)
      t[ty + r * 8][tx] = W[(size_t)(k0 + ty + r * 8) * DM + n0 + tx];
    __syncthreads();
#pragma unroll
    for (int r = 0; r < 4; r++)
      dst[(size_t)(n0 + ty + r * 8) * DM + k0 + tx] =
          __float2bfloat16(t[tx][ty + r * 8]);
  } else {
    for (int i = tid; i < NQKV; i += 256)
      bcat[i] = (i < 512) ? bq[i] : (i < 1024) ? bk[i - 512] : bv[i - 1024];
  }
}

// ---------------------------------------------------------------------------
// QKV GEMM (r13 best config): qkv = xb @ Wtqkv^T + bcat, bf16 out.
// 256x192 tile, BK=64, 8 waves, 32x32x16 MFMA, stage-ahead dbuf.
// attn_out zero-fill piggybacked: exactly 4 f32x4/thread/K-step.
// ---------------------------------------------------------------------------
__global__ __launch_bounds__(512) void qkv_gemm(
    const __hip_bfloat16* __restrict__ A, const __hip_bfloat16* __restrict__ Bt,
    const float* __restrict__ bias, __hip_bfloat16* __restrict__ C,
    float* __restrict__ fill) {
  __shared__ __align__(16) char smem[114688];   // 2 x (32K A + 24K B)

  // XCD-aware bijective swizzle (grid 256, 32 M-tiles x 8 N-tiles)
  int lin = blockIdx.x;
  lin = (lin & 7) * 32 + (lin >> 3);
  const int bm = (lin >> 3) * 256;
  const int bn = (lin & 7) * 192;

  const int tid = threadIdx.x;
  const int lane = tid & 63, wave = tid >> 6;
  const int wr = wave >> 1, wc = wave & 1;      // 4M x 2N wave grid
  const int l31 = lane & 31, lhi = lane >> 5;
  const int gtid = blockIdx.x * 512 + tid;      // for fill
  constexpr int GSTRIDE = 256 * 512;            // 131072

  f32x16 acc[2][3] = {};

  auto STAGE = [&](int buf, int k0) {
    char* base = smem + buf * 57344;
#pragma unroll
    for (int it = 0; it < 4; ++it) {
      const int g = it * 512 + tid;
      const int row = g >> 3, ch = g & 7;
      const int src_ch = ch ^ (row & 7);        // inverse swizzle on SOURCE
      gload_lds16(A + (size_t)(bm + row) * DM + k0 + src_ch * 8,
                  base + (it * 512 + wave * 64) * 16);
    }
    char* baseB = base + 32768;
#pragma unroll
    for (int it = 0; it < 3; ++it) {
      const int g = it * 512 + tid;
      const int row = g >> 3, ch = g & 7;
      const int src_ch = ch ^ (row & 7);
      gload_lds16(Bt + (size_t)(bn + row) * DM + k0 + src_ch * 8,
                  baseB + (it * 512 + wave * 64) * 16);
    }
  };

  STAGE(0, 0);  // prologue

  for (int t = 0; t < 8; ++t) {
    __syncthreads();              // drains stage(t) (+ previous fills)
    if (t < 7) STAGE((t + 1) & 1, (t + 1) * 64);

    // fill: 4 f32x4 per thread per step (256*512*8*4 = 4,194,304 exact)
    {
      f32x4 z = {0.f, 0.f, 0.f, 0.f};
#pragma unroll
      for (int j = 0; j < 4; ++j)
        __builtin_nontemporal_store(z, (f32x4*)fill + gtid + (t * 4 + j) * GSTRIDE);
    }

    const char* As = smem + (t & 1) * 57344;
    const char* Bs = As + 32768;
#pragma unroll
    for (int kk = 0; kk < 4; ++kk) {   // 4 x K=16 sub-steps
      short8 a[2], b[3];
#pragma unroll
      for (int fi = 0; fi < 2; ++fi) {
        const int row = wr * 64 + fi * 32 + l31;
        const int ch = (kk * 2 + lhi) ^ (row & 7);
        a[fi] = *(const short8*)(As + row * 128 + ch * 16);
      }
#pragma unroll
      for (int fj = 0; fj < 3; ++fj) {
        const int row = wc * 96 + fj * 32 + l31;
        const int ch = (kk * 2 + lhi) ^ (row & 7);
        b[fj] = *(const short8*)(Bs + row * 128 + ch * 16);
      }
#pragma unroll
      for (int fi = 0; fi < 2; ++fi)
#pragma unroll
        for (int fj = 0; fj < 3; ++fj)
          acc[fi][fj] = __builtin_amdgcn_mfma_f32_32x32x16_bf16(
              a[fi], b[fj], acc[fi][fj], 0, 0, 0);
    }
  }

  // ---- epilogue: stage C in LDS (96 KB bf16), store coalesced ----
  __syncthreads();
  unsigned short (*Cs)[192] = (unsigned short (*)[192])smem;
#pragma unroll
  for (int fj = 0; fj < 3; ++fj) {
    const int col = wc * 96 + fj * 32 + l31;
    const float bv = bias[bn + col];
#pragma unroll
    for (int fi = 0; fi < 2; ++fi)
#pragma unroll
      for (int r = 0; r < 16; ++r) {
        const int row = wr * 64 + fi * 32 + (r & 3) + 8 * (r >> 2) + 4 * lhi;
        Cs[row][col] = f2bf(acc[fi][fj][r] + bv);
      }
  }
  __syncthreads();
#pragma unroll
  for (int it = 0; it < 12; ++it) {
    const int g = it * 512 + tid;       // 6144 chunks of 8 bf16, 24 per row
    const int row = g / 24, ch = g % 24;
    *(uint4*)(C + (size_t)(bm + row) * NQKV + bn + ch * 8) =
        *(const uint4*)&Cs[row][ch * 8];
  }
}

// ---------------------------------------------------------------------------
// O GEMM (NEW: stage-ahead dbuf, same proven pattern as qkv_gemm):
// out[8192,512] f32 = ctx[8192,512]bf16 @ Wot^T + bo.
// 128x128 tile, BK=64, 4 waves (2x2), 32x32x16 MFMA, LDS 64KB (2 blocks/CU).
// ---------------------------------------------------------------------------
__global__ __launch_bounds__(256) void o_gemm(
    const __hip_bfloat16* __restrict__ A, const __hip_bfloat16* __restrict__ Bt,
    const float* __restrict__ bias, float* __restrict__ C) {
  __shared__ __align__(16) char smem[65536];   // 2 x (16K A + 16K B)

  // XCD-aware bijective swizzle (grid 256, 64 M-tiles x 4 N-tiles)
  int lin = blockIdx.x;
  lin = (lin & 7) * 32 + (lin >> 3);
  const int bm = (lin >> 2) * 128;
  const int bn = (lin & 3) * 128;

  const int tid = threadIdx.x;
  const int lane = tid & 63, wave = tid >> 6;
  const int wr = wave >> 1, wc = wave & 1;
  const int l31 = lane & 31, lhi = lane >> 5;

  f32x16 acc[2][2] = {};

  auto STAGE = [&](int buf, int k0) {
    char* base = smem + buf * 32768;
#pragma unroll
    for (int it = 0; it < 4; ++it) {
      const int g = it * 256 + tid;
      const int row = g >> 3, ch = g & 7;
      const int src_ch = ch ^ (row & 7);
      gload_lds16(A + (size_t)(bm + row) * DM + k0 + src_ch * 8,
                  base + (it * 256 + wave * 64) * 16);
    }
    char* baseB = base + 16384;
#pragma unroll
    for (int it = 0; it < 4; ++it) {
      const int g = it * 256 + tid;
      const int row = g >> 3, ch = g & 7;
      const int src_ch = ch ^ (row & 7);
      gload_lds16(Bt + (size_t)(bn + row) * DM + k0 + src_ch * 8,
                  baseB + (it * 256 + wave * 64) * 16);
    }
  };

  STAGE(0, 0);

  for (int t = 0; t < 8; ++t) {
    __syncthreads();
    if (t < 7) STAGE((t + 1) & 1, (t + 1) * 64);

    const char* As = smem + (t & 1) * 32768;
    const char* Bs = As + 16384;
#pragma unroll
    for (int kk = 0; kk < 4; ++kk) {
      short8 a[2], b[2];
#pragma unroll
      for (int fi = 0; fi < 2; ++fi) {
        const int row = wr * 64 + fi * 32 + l31;
        const int ch = (kk * 2 + lhi) ^ (row & 7);
        a[fi] = *(const short8*)(As + row * 128 + ch * 16);
      }
#pragma unroll
      for (int fj = 0; fj < 2; ++fj) {
        const int row = wc * 64 + fj * 32 + l31;
        const int ch = (kk * 2 + lhi) ^ (row & 7);
        b[fj] = *(const short8*)(Bs + row * 128 + ch * 16);
      }
#pragma unroll
      for (int fi = 0; fi < 2; ++fi)
#pragma unroll
        for (int fj = 0; fj < 2; ++fj)
          acc[fi][fj] = __builtin_amdgcn_mfma_f32_32x32x16_bf16(
              a[fi], b[fj], acc[fi][fj], 0, 0, 0);
    }
  }

  // Epilogue: f32 staged through LDS in two 64-row halves (32 KB region).
  __syncthreads();
  float (*Cs)[128] = (float (*)[128])smem;
#pragma unroll
  for (int half = 0; half < 2; ++half) {
    if (wr == half) {
#pragma unroll
      for (int fj = 0; fj < 2; ++fj) {
        const float bv = bias[bn + wc * 64 + fj * 32 + l31];
        const int col = wc * 64 + fj * 32 + l31;
#pragma unroll
        for (int fi = 0; fi < 2; ++fi)
#pragma unroll
          for (int r = 0; r < 16; ++r) {
            const int row = fi * 32 + (r & 3) + 8 * (r >> 2) + 4 * lhi;
            Cs[row][col] = acc[fi][fj][r] + bv;
          }
      }
    }
    __syncthreads();
#pragma unroll
    for (int t = 0; t < 8; ++t) {
      const int g = t * 256 + tid;
      const int row = g >> 5, ch = g & 31;
      *(float4*)(C + (size_t)(bm + half * 64 + row) * DM + bn + ch * 4) =
          *(const float4*)&Cs[row][ch * 4];
    }
    __syncthreads();
  }
}

// ---------------------------------------------------------------------------
// Banded causal attention -- one wave per row (r13 best structure).
// Only change vs r13: expf -> __expf (single v_exp_f32 instead of ~20-inst
// libm expansion; 11 exps/lane in a VALU-heavy kernel).
// attn_out pre-zeroed by QKV GEMM's fill; only band entries written here.
// ---------------------------------------------------------------------------
__global__ __launch_bounds__(256) void band_attn(
    const __hip_bfloat16* __restrict__ qkv, const float* __restrict__ decay_p,
    __hip_bfloat16* __restrict__ ctx, float* __restrict__ attn_out) {
  __shared__ float dlds[LAG + 1];
  const int tid = threadIdx.x;
  if (tid <= LAG) {
    float p = decay_p[tid];
    float sp = fmaxf(p, 0.0f) + log1pf(expf(-fabsf(p)));  // stable softplus
    dlds[tid] = -logf(sp + 1e-8f);
  }
  __syncthreads();

  const int blk = blockIdx.x;                  // 0..2047
  const int wave = tid >> 6, lane = tid & 63;
  const int bi = ((blk & 7) << 10) + ((blk >> 3) << 2) + wave;  // XCD-affine
  const int b = bi >> 11;
  const int i = bi & (SEQ - 1);
  const int jlo = (i >= LAG) ? (i - LAG) : 0;
  const int nj = i - jlo + 1;

  // q: 16B/lane (dims 8*lane..8*lane+7)
  const uint4 qu = *(const uint4*)(
      (const unsigned short*)(qkv + (size_t)bi * NQKV) + lane * 8);
  const unsigned short* qp = (const unsigned short*)&qu;
  float qf[8];
#pragma unroll
  for (int e = 0; e < 8; ++e) qf[e] = bf2f(qp[e]);

  // scores: 11 dots, all heads at once
  float s[LAG + 1];
#pragma unroll
  for (int jj = 0; jj <= LAG; ++jj) {
    const int j = jlo + jj;
    const bool ok = (j <= i);
    const int jc = ok ? j : i;
    const uint4 ku = *(const uint4*)(
        (const unsigned short*)(qkv + ((size_t)b * SEQ + jc) * NQKV + DM) + lane * 8);
    const unsigned short* kp = (const unsigned short*)&ku;
    float part = 0.0f;
#pragma unroll
    for (int e = 0; e < 8; ++e) part += qf[e] * bf2f(kp[e]);
    part += __shfl_xor(part, 1);
    part += __shfl_xor(part, 2);
    part += __shfl_xor(part, 4);   // lanes 8h..8h+7 now hold q_h . k_h
    s[jj] = ok ? (part * 0.125f + dlds[i - j]) : -1e30f;
  }

  // softmax over band (in-register; identical within each 8-lane head group)
  float mx = -1e30f;
#pragma unroll
  for (int jj = 0; jj <= LAG; ++jj) mx = fmaxf(mx, s[jj]);
  float sum = 0.0f;
#pragma unroll
  for (int jj = 0; jj <= LAG; ++jj) { s[jj] = __expf(s[jj] - mx); sum += s[jj]; }
  const float inv = 1.0f / sum;

  // PV accumulate (8 dims/lane); keep p in s[] for the head-mean
  float c[8] = {};
#pragma unroll
  for (int jj = 0; jj <= LAG; ++jj) {
    const float p = s[jj] * inv;
    s[jj] = p;
    const int j = jlo + jj;
    const int jc = (j <= i) ? j : i;
    const uint4 vu = *(const uint4*)(
        (const unsigned short*)(qkv + ((size_t)b * SEQ + jc) * NQKV + 2 * DM) + lane * 8);
    const unsigned short* vp = (const unsigned short*)&vu;
#pragma unroll
    for (int e = 0; e < 8; ++e) c[e] += p * bf2f(vp[e]);
  }

  // ctx store: pack 8 f32 -> 16B per lane (coalesced 1KB/row)
  unsigned short co[8];
#pragma unroll
  for (int e = 0; e < 8; ++e) co[e] = f2bf(c[e]);
  *(uint4*)((unsigned short*)(ctx + (size_t)bi * DM) + lane * 8) = *(const uint4*)co;

  // attn.mean over heads: reduce p across the 8 head groups (masks 8,16,32)
#pragma unroll
  for (int jj = 0; jj <= LAG; ++jj) {
    float a = s[jj];
    a += __shfl_xor(a, 8);
    a += __shfl_xor(a, 16);
    a += __shfl_xor(a, 32);        // all lanes: sum over 8 heads
    if (lane == jj && jj < nj)
      __builtin_nontemporal_store(a * 0.125f,
                                  attn_out + (size_t)bi * SEQ + jlo + jj);
  }
}

// ---------------------------------------------------------------------------
extern "C" void kernel_launch(void* const* d_in, const int* in_sizes, int n_in,
                              void* d_out, int out_size, void* d_ws, size_t ws_size,
                              hipStream_t stream) {
  const float* x   = (const float*)d_in[0];
  const float* Wq  = (const float*)d_in[1];
  const float* bq  = (const float*)d_in[2];
  const float* Wk  = (const float*)d_in[3];
  const float* bk  = (const float*)d_in[4];
  const float* Wv  = (const float*)d_in[5];
  const float* bv  = (const float*)d_in[6];
  const float* Wo  = (const float*)d_in[7];
  const float* bo  = (const float*)d_in[8];
  const float* dec = (const float*)d_in[9];

  float* out      = (float*)d_out;                 // [B,S,D]
  float* attn_out = out + OUT0_ELEMS;              // [B,S,S]

  // Workspace layout (16B-aligned), ~44 MB
  char* w = (char*)d_ws;
  __hip_bfloat16* xb    = (__hip_bfloat16*)w;  w += (size_t)MROWS * DM * 2;
  __hip_bfloat16* Wtqkv = (__hip_bfloat16*)w;  w += (size_t)NQKV * DM * 2;
  __hip_bfloat16* Wot   = (__hip_bfloat16*)w;  w += (size_t)DM * DM * 2;
  float*          bcat  = (float*)w;           w += (size_t)NQKV * 4;
  __hip_bfloat16* qkv   = (__hip_bfloat16*)w;  w += (size_t)MROWS * NQKV * 2;
  __hip_bfloat16* ctxb  = (__hip_bfloat16*)w;

  prep<<<3073, 256, 0, stream>>>(x, Wq, Wk, Wv, Wo, bq, bk, bv,
                                 xb, Wtqkv, Wot, bcat);

  // Fused QKV projection (256x192 tile, dbuf stage-ahead, + attn_out fill)
  qkv_gemm<<<256, 512, 0, stream>>>(xb, Wtqkv, bcat, qkv, attn_out);

  band_attn<<<2048, 256, 0, stream>>>(qkv, dec, ctxb, attn_out);

  // Output projection (dbuf stage-ahead): [8192,512] @ [512,512] -> f32 out
  o_gemm<<<256, 256, 0, stream>>>(ctxb, Wot, bo, out);
}